// Round 10
// baseline (538.963 us; speedup 1.0000x reference)
//
#include <hip/hip_runtime.h>
#include <math.h>

// ComplexPolarTransformerBeta — round 18: safe micro-bundle on the 497us/530us base.
// r9 post-mortem: bar_lds+guards were kernel-neutral (wall win was prep fusion);
// VALUBusy rose 30->33 (guard branches). This round, arithmetic-identical:
//  (1) revert GEMM prefetch guards to branch-free clamped rotation (r15 form);
//  (2) preloaded-kb0 TW GEMMs: first W-frag loads hoisted ABOVE the preceding
//      bar_lds (emb x2, T, rp x2) — globals ride across lgkm-only barriers, so
//      the ~500cy first-fragment latency hides under the stage/barrier phase;
//  (3) stageB64 scale-free variant (5 of 6 calls use scl=1; drops 8 muls each).
// absmax must stay exactly 0.0625; WRITE_SIZE ~32KB (spill check). Structure
// (QK-fused algebra, 512-thr, 2 waves/SIMD, 12 bar/layer) unchanged — every
// barrier is a genuine cross-wave k-redistribution (k spans all waves' data).

typedef __attribute__((ext_vector_type(8)))  short s16x8;
typedef __attribute__((ext_vector_type(16))) float f32x16;

#define STR  136      // LDS row stride (shorts): 128 data + 8 pad
#define LOFS 17408    // lo-plane offset within a region (shorts)
#define MFMA(a, b, c) __builtin_amdgcn_mfma_f32_32x32x16_bf16(a, b, c, 0, 0, 0)
#define ROWP(reg) (((reg) & 3) + (((reg) >> 2) << 3) + (h5 << 2))

__device__ __forceinline__ void bar_lds() {
  asm volatile("s_waitcnt lgkmcnt(0)" ::: "memory");
  __builtin_amdgcn_s_barrier();
  __builtin_amdgcn_sched_barrier(0);
}

__device__ __forceinline__ unsigned short bfhi(float x) {
  unsigned u = __float_as_uint(x);
  return (unsigned short)((u + 0x7FFFu + ((u >> 16) & 1u)) >> 16);
}
__device__ __forceinline__ float bf2f(unsigned short h) {
  return __uint_as_float(((unsigned)h) << 16);
}

// Load one W fragment pair (hi/lo) for (mtile, kb).
__device__ __forceinline__ void ldW(const short* W, int mtile, int kb, int lane,
                                    s16x8& ah, s16x8& al) {
  const short* p = W + (((mtile * 8 + kb) * 64 + lane) * 8);
  ah = *(const s16x8*)p;
  al = *(const s16x8*)(p + 32768);
}

// Stage one C-layout tile (scl=1): hi via cvt_pk; lo = exact residual of hi.
__device__ __forceinline__ void stageB64(short* SH, const f32x16& acc, int row,
                                         int colbase, int h5) {
  #pragma unroll
  for (int q = 0; q < 4; ++q) {
    int col = colbase + 8 * q + 4 * h5;
    float v0 = acc[4*q+0], v1 = acc[4*q+1], v2 = acc[4*q+2], v3 = acc[4*q+3];
    unsigned u01, u23;
    asm("v_cvt_pk_bf16_f32 %0, %1, %2" : "=v"(u01) : "v"(v0), "v"(v1));
    asm("v_cvt_pk_bf16_f32 %0, %1, %2" : "=v"(u23) : "v"(v2), "v"(v3));
    float r0 = v0 - __uint_as_float(u01 << 16);
    float r1 = v1 - __uint_as_float(u01 & 0xFFFF0000u);
    float r2 = v2 - __uint_as_float(u23 << 16);
    float r3 = v3 - __uint_as_float(u23 & 0xFFFF0000u);
    unsigned l01, l23;
    asm("v_cvt_pk_bf16_f32 %0, %1, %2" : "=v"(l01) : "v"(r0), "v"(r1));
    asm("v_cvt_pk_bf16_f32 %0, %1, %2" : "=v"(l23) : "v"(r2), "v"(r3));
    uint2 hi2; hi2.x = u01; hi2.y = u23;
    uint2 lo2; lo2.x = l01; lo2.y = l23;
    *(uint2*)(SH + row * STR + col) = hi2;
    *(uint2*)(SH + LOFS + row * STR + col) = lo2;
  }
}

// Scaled variant (Ts only).
__device__ __forceinline__ void stageB64s(short* SH, const f32x16& acc, int row,
                                          int colbase, int h5, float scl) {
  #pragma unroll
  for (int q = 0; q < 4; ++q) {
    int col = colbase + 8 * q + 4 * h5;
    float v0 = acc[4*q+0] * scl, v1 = acc[4*q+1] * scl;
    float v2 = acc[4*q+2] * scl, v3 = acc[4*q+3] * scl;
    unsigned u01, u23;
    asm("v_cvt_pk_bf16_f32 %0, %1, %2" : "=v"(u01) : "v"(v0), "v"(v1));
    asm("v_cvt_pk_bf16_f32 %0, %1, %2" : "=v"(u23) : "v"(v2), "v"(v3));
    float r0 = v0 - __uint_as_float(u01 << 16);
    float r1 = v1 - __uint_as_float(u01 & 0xFFFF0000u);
    float r2 = v2 - __uint_as_float(u23 << 16);
    float r3 = v3 - __uint_as_float(u23 & 0xFFFF0000u);
    unsigned l01, l23;
    asm("v_cvt_pk_bf16_f32 %0, %1, %2" : "=v"(l01) : "v"(r0), "v"(r1));
    asm("v_cvt_pk_bf16_f32 %0, %1, %2" : "=v"(l23) : "v"(r2), "v"(r3));
    uint2 hi2; hi2.x = u01; hi2.y = u23;
    uint2 lo2; lo2.x = l01; lo2.y = l23;
    *(uint2*)(SH + row * STR + col) = hi2;
    *(uint2*)(SH + LOFS + row * STR + col) = lo2;
  }
}

// acc[j] += Wfrag(m-tile)^ * B(LDS rows 32*(ttb+j)+l31). Preloaded kb0 W frags;
// clamped (branch-free) one-deep rotation for kb>=1.
__device__ __forceinline__ void gemmTW2p(f32x16* acc, const short* W, const short* BH,
                                         int mtile, int kbN, int ttb, int l31, int h5,
                                         int lane, s16x8 ah, s16x8 al) {
  #pragma unroll 1
  for (int kb = 0; kb < kbN; ++kb) {
    int nk = (kb + 1 < kbN) ? kb + 1 : kb;
    s16x8 nah, nal;
    ldW(W, mtile, nk, lane, nah, nal);
    int k0 = kb * 16 + 8 * h5;
    #pragma unroll
    for (int j = 0; j < 2; ++j) {
      int brow = 32 * (ttb + j) + l31;
      s16x8 bh = *(const s16x8*)(BH + brow * STR + k0);
      s16x8 bl = *(const s16x8*)(BH + LOFS + brow * STR + k0);
      acc[j] = MFMA(ah, bh, acc[j]);
      acc[j] = MFMA(ah, bl, acc[j]);
      acc[j] = MFMA(al, bh, acc[j]);
    }
    ah = nah; al = nal;
  }
}

// acc[j] += A(LDS rows mblk+l31) * Wfrag(n-tile=ttb+j). A prefetched (clamped).
__device__ __forceinline__ void gemmNW2(f32x16* acc, const short* AH, const short* W,
                                        int mblk, int ttb, int l31, int h5, int lane) {
  int arow = mblk + l31;
  const short* ap0 = AH + arow * STR + 8 * h5;
  s16x8 ah = *(const s16x8*)ap0;
  s16x8 al = *(const s16x8*)(ap0 + LOFS);
  #pragma unroll 1
  for (int kb = 0; kb < 8; ++kb) {
    int nk0 = ((kb < 7) ? kb + 1 : 7) * 16 + 8 * h5;
    s16x8 nah = *(const s16x8*)(AH + arow * STR + nk0);
    s16x8 nal = *(const s16x8*)(AH + LOFS + arow * STR + nk0);
    #pragma unroll
    for (int j = 0; j < 2; ++j) {
      const short* wp = W + ((((ttb + j) * 8 + kb) * 64 + lane) * 8);
      s16x8 bh = *(const s16x8*)wp;
      s16x8 bl = *(const s16x8*)(wp + 32768);
      acc[j] = MFMA(ah, bh, acc[j]);
      acc[j] = MFMA(ah, bl, acc[j]);
      acc[j] = MFMA(al, bh, acc[j]);
    }
    ah = nah; al = nal;
  }
}

// acc[j] += A(LDS rows mblk+l31) * B(LDS rows 32*(ttb+j)+l31)^T. A prefetched (clamped).
__device__ __forceinline__ void gemmLL2(f32x16* acc, const short* AH, const short* BH,
                                        int mblk, int ttb, int l31, int h5) {
  int arow = mblk + l31;
  const short* ap0 = AH + arow * STR + 8 * h5;
  s16x8 ah = *(const s16x8*)ap0;
  s16x8 al = *(const s16x8*)(ap0 + LOFS);
  #pragma unroll 1
  for (int kb = 0; kb < 8; ++kb) {
    int nk0 = ((kb < 7) ? kb + 1 : 7) * 16 + 8 * h5;
    s16x8 nah = *(const s16x8*)(AH + arow * STR + nk0);
    s16x8 nal = *(const s16x8*)(AH + LOFS + arow * STR + nk0);
    int k0 = kb * 16 + 8 * h5;
    #pragma unroll
    for (int j = 0; j < 2; ++j) {
      int brow = 32 * (ttb + j) + l31;
      s16x8 bh = *(const s16x8*)(BH + brow * STR + k0);
      s16x8 bl = *(const s16x8*)(BH + LOFS + brow * STR + k0);
      acc[j] = MFMA(ah, bh, acc[j]);
      acc[j] = MFMA(ah, bl, acc[j]);
      acc[j] = MFMA(al, bh, acc[j]);
    }
    ah = nah; al = nal;
  }
}

// ---------------- unified prep: W' computed inline (mids 0-3) + u, then pack ----
__global__ __launch_bounds__(512)
void prep_kernel(const float* __restrict__ Wq, const float* __restrict__ Wk,
                 const float* __restrict__ bq,
                 const float* __restrict__ Wvm, const float* __restrict__ Wvp,
                 const float* __restrict__ rp_W,
                 const float* __restrict__ emb_Wm, const float* __restrict__ emb_Wp,
                 short* __restrict__ ws, float* __restrict__ u) {
  __shared__ float WqS[128 * 129];
  __shared__ float WkS[32 * 129];
  int mid = blockIdx.x >> 2, hblk = blockIdx.x & 3;
  int t = threadIdx.x;
  int kb = t >> 6, lane = t & 63;
  int h = hblk * 32 + (lane & 31);
  int kbase = kb * 16 + ((lane >> 5) << 3);
  float val[8];
  if (mid < 4) {
    const float* wq = Wq + (size_t)mid * 16384;
    const float* wk = Wk + (size_t)mid * 16384 + (size_t)hblk * 32 * 128;
    for (int idx = t; idx < 16384; idx += 512)
      WqS[(idx >> 7) * 129 + (idx & 127)] = wq[idx];
    for (int idx = t; idx < 4096; idx += 512)
      WkS[(idx >> 7) * 129 + (idx & 127)] = wk[idx];
    __syncthreads();
    int hl = lane & 31;
    #pragma unroll
    for (int j = 0; j < 8; ++j) val[j] = 0.f;
    for (int c = 0; c < 128; ++c) {
      float wkv = WkS[hl * 129 + c];
      #pragma unroll
      for (int j = 0; j < 8; ++j)
        val[j] += WqS[(kbase + j) * 129 + c] * wkv;
    }
    if (t < 32) {
      float s = 0.f;
      const float* bql = bq + mid * 128;
      for (int c = 0; c < 128; ++c) s += WkS[t * 129 + c] * bql[c];
      u[mid * 128 + hblk * 32 + t] = 0.08838834764831845f * s;
    }
  } else {
    const float* src;
    int krows = 128;
    if (mid < 8)        src = Wvm + (size_t)(mid - 4) * 16384;
    else if (mid < 12)  src = Wvp + (size_t)(mid - 8) * 16384;
    else if (mid == 12) src = rp_W;
    else if (mid == 13) src = rp_W + 16384;
    else if (mid == 14) { src = emb_Wm; krows = 19; }
    else                { src = emb_Wp; krows = 19; }
    #pragma unroll
    for (int j = 0; j < 8; ++j) {
      int k = kbase + j;
      val[j] = (k < krows) ? src[(size_t)k * 128 + h] : 0.f;
    }
  }
  s16x8 H, L;
  #pragma unroll
  for (int j = 0; j < 8; ++j) {
    unsigned short hi = bfhi(val[j]);
    H[j] = (short)hi;
    L[j] = (short)bfhi(val[j] - bf2f(hi));
  }
  short* dst = ws + (size_t)mid * 65536 + ((hblk * 8 + kb) * 64 + lane) * 8;
  *(s16x8*)dst = H;
  *(s16x8*)(dst + 32768) = L;
}

// ---------------- main kernel ----------------
__global__ __launch_bounds__(512, 2)
void cpt_kernel(const float* __restrict__ atom_types,
                const float* __restrict__ coords,
                const int*   __restrict__ edge_index,
                const float* __restrict__ edge_attr,
                const float* __restrict__ emb_bm, const float* __restrict__ emb_bp,
                const float* __restrict__ bvm, const float* __restrict__ bvp,
                const float* __restrict__ We,  const float* __restrict__ be,
                const float* __restrict__ dist_scale,
                const float* __restrict__ ln_g, const float* __restrict__ ln_b,
                const float* __restrict__ rp_b,
                const float* __restrict__ h1_W, const float* __restrict__ h1_b,
                const float* __restrict__ h2_W, const float* __restrict__ h2_b,
                const short* __restrict__ wpre, const float* __restrict__ uArr,
                float* __restrict__ out)
{
  __shared__ __align__(16) short R1s[34816];
  __shared__ __align__(16) short R2s[34816];
  __shared__ float SCa[512];
  __shared__ float SCb[512];

  const int t = threadIdx.x, b = blockIdx.x;
  const int w = t >> 6, lane = t & 63, l31 = lane & 31, h5 = lane >> 5;
  const int wm = w >> 1, ttb = (w & 1) << 1;
  const int mblk = wm << 5;
  const float scale = 0.08838834764831845f;  // 1/sqrt(128)

  // ---- stage x (atom_types||coords, k padded to 32) into R1 as bf16 hi/lo ----
  if (t < 128) {
    const float* xr = atom_types + ((size_t)b * 128 + t) * 16;
    const float* cr = coords + ((size_t)b * 128 + t) * 3;
    float xv[19];
    float4 a0 = *(const float4*)xr,       a1 = *(const float4*)(xr + 4);
    float4 a2 = *(const float4*)(xr + 8), a3 = *(const float4*)(xr + 12);
    xv[0]=a0.x; xv[1]=a0.y; xv[2]=a0.z; xv[3]=a0.w;
    xv[4]=a1.x; xv[5]=a1.y; xv[6]=a1.z; xv[7]=a1.w;
    xv[8]=a2.x; xv[9]=a2.y; xv[10]=a2.z; xv[11]=a2.w;
    xv[12]=a3.x; xv[13]=a3.y; xv[14]=a3.z; xv[15]=a3.w;
    xv[16]=cr[0]; xv[17]=cr[1]; xv[18]=cr[2];
    #pragma unroll
    for (int k = 0; k < 32; ++k) {
      float v = (k < 19) ? xv[k] : 0.f;
      unsigned short hh = bfhi(v);
      R1s[t * STR + k] = (short)hh;
      R1s[LOFS + t * STR + k] = (short)bfhi(v - bf2f(hh));
    }
  }
  // hoist embedding kb0 W frags above the barrier (ride across bar_lds)
  s16x8 eMah, eMal, ePah, ePal;
  ldW(wpre + (size_t)14 * 65536, wm, 0, lane, eMah, eMal);
  ldW(wpre + (size_t)15 * 65536, wm, 0, lane, ePah, ePal);
  bar_lds();

  // ---- embedding via MFMA: magT/phT (TRANSPOSED: h=32wm+ROWP(reg), a=32(ttb+j)+l31) ----
  f32x16 magT[2], phT[2];
  {
    #pragma unroll
    for (int reg = 0; reg < 16; ++reg) {
      float bm = emb_bm[32 * wm + ROWP(reg)];
      float bp = emb_bp[32 * wm + ROWP(reg)];
      #pragma unroll
      for (int j = 0; j < 2; ++j) { magT[j][reg] = bm; phT[j][reg] = bp; }
    }
    gemmTW2p(magT, wpre + (size_t)14 * 65536, R1s, wm, 2, ttb, l31, h5, lane, eMah, eMal);
    gemmTW2p(phT,  wpre + (size_t)15 * 65536, R1s, wm, 2, ttb, l31, h5, lane, ePah, ePal);
  }

  // ---- layers ----
  for (int l = 0; l < 4; ++l) {
    const short* wpP  = wpre + (size_t)l * 65536;        // W' pack
    const short* wvmP = wpre + (size_t)(4 + l) * 65536;
    const short* wvpP = wpre + (size_t)(8 + l) * 65536;
    float* Bf = (float*)R2s;                             // 128x128 bias, [j][i]

    bar_lds();                                       // prior layer readers done
    #pragma unroll
    for (int j = 0; j < 2; ++j)
      stageB64(R1s, magT[j], 32 * (ttb + j) + l31, mblk, h5);  // mag[a][h] -> R1
    {
      float4 z4 = make_float4(0.f, 0.f, 0.f, 0.f);
      #pragma unroll
      for (int k = 0; k < 8; ++k) *(float4*)(Bf + (t + 512 * k) * 4) = z4;
    }
    // v partials: v_a = sum_h mag[a][h] * u[h]  (this wave's 32-h block)
    {
      float ur[16];
      #pragma unroll
      for (int reg = 0; reg < 16; ++reg) ur[reg] = uArr[l * 128 + 32 * wm + ROWP(reg)];
      #pragma unroll
      for (int j = 0; j < 2; ++j) {
        float p = 0.f;
        #pragma unroll
        for (int reg = 0; reg < 16; ++reg) p += magT[j][reg] * ur[reg];
        p += __shfl_xor(p, 32);
        if (h5 == 0) SCa[wm * 128 + 32 * (ttb + j) + l31] = p;
      }
    }
    // edge-bias global loads + T-GEMM kb0 W frags hoisted above the barrier
    int e0h[2], e1h[2]; float bvh[2];
    {
      float w0 = We[l*4], w1 = We[l*4+1], w2 = We[l*4+2], w3 = We[l*4+3];
      float bel = be[l], dsl = dist_scale[l];
      #pragma unroll
      for (int k = 0; k < 2; ++k) {
        int e = t + 512 * k;
        e0h[k] = edge_index[(size_t)b * 2048 + e];
        e1h[k] = edge_index[(size_t)b * 2048 + 1024 + e];
        float4 ea = *(const float4*)(edge_attr + ((size_t)b * 1024 + e) * 4);
        bvh[k] = ea.x*w0 + ea.y*w1 + ea.z*w2 + ea.w*w3 + bel + dsl*ea.x;
      }
    }
    s16x8 tAh, tAl;
    ldW(wpP, wm, 0, lane, tAh, tAl);
    bar_lds();                                       // mag/Bf-zero/v ready

    // edge bias scatter: Bf[j][i] += bval
    #pragma unroll
    for (int k = 0; k < 2; ++k)
      atomicAdd(&Bf[e1h[k] * 128 + e0h[k]], bvh[k]);

    // T = mag @ W'  (accT: m=b'=32wm+ROWP, n=i=32(ttb+j)+l31); mag stays in R1
    f32x16 accT[2];
    #pragma unroll
    for (int j = 0; j < 2; ++j)
      #pragma unroll
      for (int reg = 0; reg < 16; ++reg) accT[j][reg] = 0.f;
    gemmTW2p(accT, wpP, R1s, wm, 8, ttb, l31, h5, lane, tAh, tAl);
    bar_lds();                                       // atomics visible

    // accS init = bias[i][j] + v_j  (m=j=32wm+ROWP, n=i=32(ttb+j)+l31)
    f32x16 accS[2];
    {
      float vj[16];
      #pragma unroll
      for (int reg = 0; reg < 16; ++reg) {
        int jj = 32 * wm + ROWP(reg);
        vj[reg] = SCa[jj] + SCa[128 + jj] + SCa[256 + jj] + SCa[384 + jj];
      }
      #pragma unroll
      for (int j = 0; j < 2; ++j) {
        #pragma unroll
        for (int reg = 0; reg < 16; ++reg)
          accS[j][reg] = Bf[(32 * wm + ROWP(reg)) * 128 + 32 * (ttb + j) + l31] + vj[reg];
      }
    }
    bar_lds();                                       // Bf reads done
    #pragma unroll
    for (int j = 0; j < 2; ++j)
      stageB64s(R2s, accT[j], 32 * (ttb + j) + l31, mblk, h5, scale);  // Ts -> R2
    bar_lds();                                       // Ts ready

    // scoresT[j][i] = mag @ Ts^T + bias + v
    gemmLL2(accS, R1s, R2s, mblk, ttb, l31, h5);

    // one-pass softmax over j: local (max, expsum) -> ONE barrier -> merge
    float mloc[2];
    #pragma unroll
    for (int j = 0; j < 2; ++j) {
      float m = accS[j][0];
      #pragma unroll
      for (int reg = 1; reg < 16; ++reg) m = fmaxf(m, accS[j][reg]);
      m = fmaxf(m, __shfl_xor(m, 32));
      mloc[j] = m;
      float s = 0.f;
      #pragma unroll
      for (int reg = 0; reg < 16; ++reg) {
        float e = __expf(accS[j][reg] - m);
        accS[j][reg] = e; s += e;
      }
      s += __shfl_xor(s, 32);
      if (h5 == 0) {
        SCa[wm * 128 + 32 * (ttb + j) + l31] = m;
        SCb[wm * 128 + 32 * (ttb + j) + l31] = s;
      }
    }
    bar_lds();                                       // (also: all Ts reads done)
    #pragma unroll
    for (int j = 0; j < 2; ++j) {
      int i = 32 * (ttb + j) + l31;
      float m0 = SCa[i], m1 = SCa[128 + i], m2 = SCa[256 + i], m3 = SCa[384 + i];
      float M = fmaxf(fmaxf(m0, m1), fmaxf(m2, m3));
      float S = SCb[i]        * __expf(m0 - M) + SCb[128 + i] * __expf(m1 - M)
              + SCb[256 + i]  * __expf(m2 - M) + SCb[384 + i] * __expf(m3 - M);
      float f = __expf(mloc[j] - M) / S;
      #pragma unroll
      for (int reg = 0; reg < 16; ++reg) accS[j][reg] *= f;
    }
    #pragma unroll
    for (int j = 0; j < 2; ++j)
      stageB64(R2s, accS[j], 32 * (ttb + j) + l31, mblk, h5);  // attn[i][j] -> R2

    // vm = mag @ Wvm (mag still resident in R1 — no restage)
    {
      f32x16 accVM[2];
      #pragma unroll
      for (int j = 0; j < 2; ++j) {
        float bv = bvm[l * 128 + 32 * (ttb + j) + l31];
        #pragma unroll
        for (int reg = 0; reg < 16; ++reg) accVM[j][reg] = bv;
      }
      gemmNW2(accVM, R1s, wvmP, mblk, ttb, l31, h5, lane);
      bar_lds();                                     // all mag reads done
      #pragma unroll
      for (int j = 0; j < 2; ++j)
        stageB64(R1s, accVM[j], 32 * (ttb + j) + l31, mblk, h5); // vmT[h][j] -> R1
      bar_lds();                                     // vm + attn ready
    }

    // new_mag^T = vm^T @ attn^T + mag^T  (accM: h=32wm+ROWP, i=32(ttb+j)+l31)
    f32x16 accM[2];
    #pragma unroll
    for (int j = 0; j < 2; ++j) accM[j] = magT[j];
    gemmLL2(accM, R1s, R2s, mblk, ttb, l31, h5);

    // LayerNorm over h: sum over regs + h5 partner + 4 m-blocks
    {
      #pragma unroll
      for (int j = 0; j < 2; ++j) {
        float s = 0.f, q = 0.f;
        #pragma unroll
        for (int reg = 0; reg < 16; ++reg) { float v = accM[j][reg]; s += v; q += v*v; }
        s += __shfl_xor(s, 32); q += __shfl_xor(q, 32);
        if (h5 == 0) {
          SCa[wm * 128 + 32 * (ttb + j) + l31] = s;
          SCb[wm * 128 + 32 * (ttb + j) + l31] = q;
        }
      }
      bar_lds();
      #pragma unroll
      for (int reg = 0; reg < 16; ++reg) {
        float gv = ln_g[l * 128 + 32 * wm + ROWP(reg)];
        float bv = ln_b[l * 128 + 32 * wm + ROWP(reg)];
        #pragma unroll
        for (int j = 0; j < 2; ++j) {
          int i = 32 * (ttb + j) + l31;
          float s = SCa[i] + SCa[128 + i] + SCa[256 + i] + SCa[384 + i];
          float q = SCb[i] + SCb[128 + i] + SCb[256 + i] + SCb[384 + i];
          float mu = s * (1.f / 128.f);
          float var = q * (1.f / 128.f) - mu * mu;
          float inv = 1.f / sqrtf(var + 1e-5f);
          magT[j][reg] = gv * ((accM[j][reg] - mu) * inv) + bv;
        }
      }
    }
    #pragma unroll
    for (int j = 0; j < 2; ++j)
      stageB64(R1s, phT[j], 32 * (ttb + j) + l31, mblk, h5);   // ph[a][h] -> R1
    bar_lds();

    // vp = ph @ Wvp (normal); staged as vpT[h][j]
    {
      f32x16 accV[2];
      #pragma unroll
      for (int j = 0; j < 2; ++j) {
        float bv = bvp[l * 128 + 32 * (ttb + j) + l31];
        #pragma unroll
        for (int reg = 0; reg < 16; ++reg) accV[j][reg] = bv;
      }
      gemmNW2(accV, R1s, wvpP, mblk, ttb, l31, h5, lane);
      bar_lds();                                     // all ph reads done
      #pragma unroll
      for (int j = 0; j < 2; ++j)
        stageB64(R1s, accV[j], 32 * (ttb + j) + l31, mblk, h5); // vpT[h][j] -> R1
      bar_lds();
    }

    // new_ph^T = vp^T @ attn^T + ph^T
    f32x16 accP[2];
    #pragma unroll
    for (int j = 0; j < 2; ++j) accP[j] = phT[j];
    gemmLL2(accP, R1s, R2s, mblk, ttb, l31, h5);
    #pragma unroll
    for (int j = 0; j < 2; ++j) phT[j] = accP[j];
  } // layers

  // ---- real/imag -> RealProjection (transposed accR: hout=32wm+ROWP, a=32(ttb+j)+l31) ----
  f32x16 reT[2], imT[2];
  #pragma unroll
  for (int j = 0; j < 2; ++j)
    #pragma unroll
    for (int reg = 0; reg < 16; ++reg) {
      float s_, c_;
      __sincosf(phT[j][reg], &s_, &c_);
      reT[j][reg] = magT[j][reg] * c_;
      imT[j][reg] = magT[j][reg] * s_;
    }
  bar_lds();
  #pragma unroll
  for (int j = 0; j < 2; ++j) {
    stageB64(R1s, reT[j], 32 * (ttb + j) + l31, mblk, h5);   // re[a][h] -> R1
    stageB64(R2s, imT[j], 32 * (ttb + j) + l31, mblk, h5);   // im[a][h] -> R2
  }
  // hoist rp kb0 W frags above the barrier
  s16x8 rAah, rAal, rBah, rBal;
  ldW(wpre + (size_t)12 * 65536, wm, 0, lane, rAah, rAal);
  ldW(wpre + (size_t)13 * 65536, wm, 0, lane, rBah, rBal);
  bar_lds();
  f32x16 accR[2];
  #pragma unroll
  for (int reg = 0; reg < 16; ++reg) {
    float bv = rp_b[32 * wm + ROWP(reg)];
    #pragma unroll
    for (int j = 0; j < 2; ++j) accR[j][reg] = bv;
  }
  gemmTW2p(accR, wpre + (size_t)12 * 65536, R1s, wm, 8, ttb, l31, h5, lane, rAah, rAal);
  gemmTW2p(accR, wpre + (size_t)13 * 65536, R2s, wm, 8, ttb, l31, h5, lane, rBah, rBal);

  // ---- pooling: column sum over atoms a (j in-thread + l31 shfl + partner wave) ----
  {
    float cs[16];
    #pragma unroll
    for (int reg = 0; reg < 16; ++reg) {
      float s = accR[0][reg] + accR[1][reg];
      s += __shfl_xor(s, 16); s += __shfl_xor(s, 8);
      s += __shfl_xor(s, 4);  s += __shfl_xor(s, 2); s += __shfl_xor(s, 1);
      cs[reg] = s;
    }
    if (l31 == 0) {
      #pragma unroll
      for (int reg = 0; reg < 16; ++reg)
        SCa[(w & 1) * 128 + 32 * wm + ROWP(reg)] = cs[reg];
    }
  }
  bar_lds();
  // h1 GEMV split 4-way over all 512 threads; combine via SCb
  {
    int col = t & 127, seg = t >> 7;
    float acc = (seg == 0) ? h1_b[col] : 0.f;
    int i0 = seg * 32;
    for (int i = i0; i < i0 + 32; ++i) {
      float c = SCa[i] + SCa[128 + i];
      acc += c * (h1_W[(size_t)i * 128 + col] * (1.f / 128.f) +
                  h1_W[(size_t)(128 + i) * 128 + col]);
    }
    SCb[t] = acc;
  }
  bar_lds();
  if (t < 128) {
    float a = SCb[t] + SCb[128 + t] + SCb[256 + t] + SCb[384 + t];
    float hv = a / (1.f + __expf(-a));   // SiLU
    SCa[t] = hv * h2_W[t];
  }
  bar_lds();
  if (t < 64) {
    float s2 = SCa[t] + SCa[64 + t];
    #pragma unroll
    for (int off = 32; off >= 1; off >>= 1) s2 += __shfl_xor(s2, off);
    if (t == 0) out[b] = s2 + h2_b[0];
  }
}

extern "C" void kernel_launch(void* const* d_in, const int* in_sizes, int n_in,
                              void* d_out, int out_size, void* d_ws, size_t ws_size,
                              hipStream_t stream) {
  const float* atom_types = (const float*)d_in[0];
  const float* coords     = (const float*)d_in[1];
  const int*   edge_index = (const int*)  d_in[2];
  const float* edge_attr  = (const float*)d_in[3];
  const float* emb_Wm = (const float*)d_in[4];
  const float* emb_bm = (const float*)d_in[5];
  const float* emb_Wp = (const float*)d_in[6];
  const float* emb_bp = (const float*)d_in[7];
  const float* Wq  = (const float*)d_in[8];
  const float* bq  = (const float*)d_in[9];
  const float* Wk  = (const float*)d_in[10];
  const float* bk  = (const float*)d_in[11];
  const float* Wvm = (const float*)d_in[12];
  const float* bvm = (const float*)d_in[13];
  const float* Wvp = (const float*)d_in[14];
  const float* bvp = (const float*)d_in[15];
  const float* We  = (const float*)d_in[16];
  const float* be  = (const float*)d_in[17];
  const float* dist_scale = (const float*)d_in[18];
  const float* ln_g = (const float*)d_in[19];
  const float* ln_b = (const float*)d_in[20];
  const float* rp_W = (const float*)d_in[21];
  const float* rp_b = (const float*)d_in[22];
  const float* h1_W = (const float*)d_in[23];
  const float* h1_b = (const float*)d_in[24];
  const float* h2_W = (const float*)d_in[25];
  const float* h2_b = (const float*)d_in[26];
  float* out = (float*)d_out;
  (void)bk;
  // workspace layout: 16 packed mats (16*131072 B) | u (512 f32)
  short* wpre = (short*)d_ws;
  float* uArr = (float*)((char*)d_ws + (size_t)16 * 131072);

  hipLaunchKernelGGL(prep_kernel, dim3(64), dim3(512), 0, stream,
                     Wq, Wk, bq, Wvm, Wvp, rp_W, emb_Wm, emb_Wp, wpre, uArr);
  hipLaunchKernelGGL(cpt_kernel, dim3(1024), dim3(512), 0, stream,
                     atom_types, coords, edge_index, edge_attr,
                     emb_bm, emb_bp,
                     bvm, bvp,
                     We, be, dist_scale, ln_g, ln_b,
                     rp_b, h1_W, h1_b, h2_W, h2_b,
                     (const short*)wpre, (const float*)uArr, out);
}

// Round 12
// 525.138 us; speedup vs baseline: 1.0263x; 1.0263x over previous
//
#include <hip/hip_runtime.h>
#include <math.h>

// ComplexPolarTransformerBeta — round 20: RESUBMIT of round 19 (container infra
// failure, no kernel verdict — same signature as round 6's flake).
// float4-interleaved cross-wave partials on the 481us base: the 4-slot
// reductions (vj, softmax merge, LN stats) move from 4x scalar ds_read_b32 @
// stride 512B to ONE aligned ds_read_b128 on an interleaved SC[i*4+src] layout
// (lane-consecutive -> conflict-free; vj reads broadcast). Sum order x+y+z+w
// unchanged -> bitwise-identical. Pooling/epilogue keep the old layout
// (barrier-separated, run once). Pre-commit: <1.5% gain => declare practical
// structural ceiling next round (MFMA floor ~136us + VALU ~159us + barrier
// serialization at LDS/VGPR-walled 2 waves/SIMD).
// absmax must stay exactly 0.0625; WRITE_SIZE ~32KB (spill check).

typedef __attribute__((ext_vector_type(8)))  short s16x8;
typedef __attribute__((ext_vector_type(16))) float f32x16;

#define STR  136      // LDS row stride (shorts): 128 data + 8 pad
#define LOFS 17408    // lo-plane offset within a region (shorts)
#define MFMA(a, b, c) __builtin_amdgcn_mfma_f32_32x32x16_bf16(a, b, c, 0, 0, 0)
#define ROWP(reg) (((reg) & 3) + (((reg) >> 2) << 3) + (h5 << 2))

__device__ __forceinline__ void bar_lds() {
  asm volatile("s_waitcnt lgkmcnt(0)" ::: "memory");
  __builtin_amdgcn_s_barrier();
  __builtin_amdgcn_sched_barrier(0);
}

__device__ __forceinline__ unsigned short bfhi(float x) {
  unsigned u = __float_as_uint(x);
  return (unsigned short)((u + 0x7FFFu + ((u >> 16) & 1u)) >> 16);
}
__device__ __forceinline__ float bf2f(unsigned short h) {
  return __uint_as_float(((unsigned)h) << 16);
}

// Load one W fragment pair (hi/lo) for (mtile, kb).
__device__ __forceinline__ void ldW(const short* W, int mtile, int kb, int lane,
                                    s16x8& ah, s16x8& al) {
  const short* p = W + (((mtile * 8 + kb) * 64 + lane) * 8);
  ah = *(const s16x8*)p;
  al = *(const s16x8*)(p + 32768);
}

// Stage one C-layout tile (scl=1): hi via cvt_pk; lo = exact residual of hi.
__device__ __forceinline__ void stageB64(short* SH, const f32x16& acc, int row,
                                         int colbase, int h5) {
  #pragma unroll
  for (int q = 0; q < 4; ++q) {
    int col = colbase + 8 * q + 4 * h5;
    float v0 = acc[4*q+0], v1 = acc[4*q+1], v2 = acc[4*q+2], v3 = acc[4*q+3];
    unsigned u01, u23;
    asm("v_cvt_pk_bf16_f32 %0, %1, %2" : "=v"(u01) : "v"(v0), "v"(v1));
    asm("v_cvt_pk_bf16_f32 %0, %1, %2" : "=v"(u23) : "v"(v2), "v"(v3));
    float r0 = v0 - __uint_as_float(u01 << 16);
    float r1 = v1 - __uint_as_float(u01 & 0xFFFF0000u);
    float r2 = v2 - __uint_as_float(u23 << 16);
    float r3 = v3 - __uint_as_float(u23 & 0xFFFF0000u);
    unsigned l01, l23;
    asm("v_cvt_pk_bf16_f32 %0, %1, %2" : "=v"(l01) : "v"(r0), "v"(r1));
    asm("v_cvt_pk_bf16_f32 %0, %1, %2" : "=v"(l23) : "v"(r2), "v"(r3));
    uint2 hi2; hi2.x = u01; hi2.y = u23;
    uint2 lo2; lo2.x = l01; lo2.y = l23;
    *(uint2*)(SH + row * STR + col) = hi2;
    *(uint2*)(SH + LOFS + row * STR + col) = lo2;
  }
}

// Scaled variant (Ts only).
__device__ __forceinline__ void stageB64s(short* SH, const f32x16& acc, int row,
                                          int colbase, int h5, float scl) {
  #pragma unroll
  for (int q = 0; q < 4; ++q) {
    int col = colbase + 8 * q + 4 * h5;
    float v0 = acc[4*q+0] * scl, v1 = acc[4*q+1] * scl;
    float v2 = acc[4*q+2] * scl, v3 = acc[4*q+3] * scl;
    unsigned u01, u23;
    asm("v_cvt_pk_bf16_f32 %0, %1, %2" : "=v"(u01) : "v"(v0), "v"(v1));
    asm("v_cvt_pk_bf16_f32 %0, %1, %2" : "=v"(u23) : "v"(v2), "v"(v3));
    float r0 = v0 - __uint_as_float(u01 << 16);
    float r1 = v1 - __uint_as_float(u01 & 0xFFFF0000u);
    float r2 = v2 - __uint_as_float(u23 << 16);
    float r3 = v3 - __uint_as_float(u23 & 0xFFFF0000u);
    unsigned l01, l23;
    asm("v_cvt_pk_bf16_f32 %0, %1, %2" : "=v"(l01) : "v"(r0), "v"(r1));
    asm("v_cvt_pk_bf16_f32 %0, %1, %2" : "=v"(l23) : "v"(r2), "v"(r3));
    uint2 hi2; hi2.x = u01; hi2.y = u23;
    uint2 lo2; lo2.x = l01; lo2.y = l23;
    *(uint2*)(SH + row * STR + col) = hi2;
    *(uint2*)(SH + LOFS + row * STR + col) = lo2;
  }
}

// acc[j] += Wfrag(m-tile)^ * B(LDS rows 32*(ttb+j)+l31). Preloaded kb0 W frags;
// clamped (branch-free) one-deep rotation for kb>=1.
__device__ __forceinline__ void gemmTW2p(f32x16* acc, const short* W, const short* BH,
                                         int mtile, int kbN, int ttb, int l31, int h5,
                                         int lane, s16x8 ah, s16x8 al) {
  #pragma unroll 1
  for (int kb = 0; kb < kbN; ++kb) {
    int nk = (kb + 1 < kbN) ? kb + 1 : kb;
    s16x8 nah, nal;
    ldW(W, mtile, nk, lane, nah, nal);
    int k0 = kb * 16 + 8 * h5;
    #pragma unroll
    for (int j = 0; j < 2; ++j) {
      int brow = 32 * (ttb + j) + l31;
      s16x8 bh = *(const s16x8*)(BH + brow * STR + k0);
      s16x8 bl = *(const s16x8*)(BH + LOFS + brow * STR + k0);
      acc[j] = MFMA(ah, bh, acc[j]);
      acc[j] = MFMA(ah, bl, acc[j]);
      acc[j] = MFMA(al, bh, acc[j]);
    }
    ah = nah; al = nal;
  }
}

// acc[j] += A(LDS rows mblk+l31) * Wfrag(n-tile=ttb+j). A prefetched (clamped).
__device__ __forceinline__ void gemmNW2(f32x16* acc, const short* AH, const short* W,
                                        int mblk, int ttb, int l31, int h5, int lane) {
  int arow = mblk + l31;
  const short* ap0 = AH + arow * STR + 8 * h5;
  s16x8 ah = *(const s16x8*)ap0;
  s16x8 al = *(const s16x8*)(ap0 + LOFS);
  #pragma unroll 1
  for (int kb = 0; kb < 8; ++kb) {
    int nk0 = ((kb < 7) ? kb + 1 : 7) * 16 + 8 * h5;
    s16x8 nah = *(const s16x8*)(AH + arow * STR + nk0);
    s16x8 nal = *(const s16x8*)(AH + LOFS + arow * STR + nk0);
    #pragma unroll
    for (int j = 0; j < 2; ++j) {
      const short* wp = W + ((((ttb + j) * 8 + kb) * 64 + lane) * 8);
      s16x8 bh = *(const s16x8*)wp;
      s16x8 bl = *(const s16x8*)(wp + 32768);
      acc[j] = MFMA(ah, bh, acc[j]);
      acc[j] = MFMA(ah, bl, acc[j]);
      acc[j] = MFMA(al, bh, acc[j]);
    }
    ah = nah; al = nal;
  }
}

// acc[j] += A(LDS rows mblk+l31) * B(LDS rows 32*(ttb+j)+l31)^T. A prefetched (clamped).
__device__ __forceinline__ void gemmLL2(f32x16* acc, const short* AH, const short* BH,
                                        int mblk, int ttb, int l31, int h5) {
  int arow = mblk + l31;
  const short* ap0 = AH + arow * STR + 8 * h5;
  s16x8 ah = *(const s16x8*)ap0;
  s16x8 al = *(const s16x8*)(ap0 + LOFS);
  #pragma unroll 1
  for (int kb = 0; kb < 8; ++kb) {
    int nk0 = ((kb < 7) ? kb + 1 : 7) * 16 + 8 * h5;
    s16x8 nah = *(const s16x8*)(AH + arow * STR + nk0);
    s16x8 nal = *(const s16x8*)(AH + LOFS + arow * STR + nk0);
    int k0 = kb * 16 + 8 * h5;
    #pragma unroll
    for (int j = 0; j < 2; ++j) {
      int brow = 32 * (ttb + j) + l31;
      s16x8 bh = *(const s16x8*)(BH + brow * STR + k0);
      s16x8 bl = *(const s16x8*)(BH + LOFS + brow * STR + k0);
      acc[j] = MFMA(ah, bh, acc[j]);
      acc[j] = MFMA(ah, bl, acc[j]);
      acc[j] = MFMA(al, bh, acc[j]);
    }
    ah = nah; al = nal;
  }
}

// ---------------- unified prep: W' computed inline (mids 0-3) + u, then pack ----
__global__ __launch_bounds__(512)
void prep_kernel(const float* __restrict__ Wq, const float* __restrict__ Wk,
                 const float* __restrict__ bq,
                 const float* __restrict__ Wvm, const float* __restrict__ Wvp,
                 const float* __restrict__ rp_W,
                 const float* __restrict__ emb_Wm, const float* __restrict__ emb_Wp,
                 short* __restrict__ ws, float* __restrict__ u) {
  __shared__ float WqS[128 * 129];
  __shared__ float WkS[32 * 129];
  int mid = blockIdx.x >> 2, hblk = blockIdx.x & 3;
  int t = threadIdx.x;
  int kb = t >> 6, lane = t & 63;
  int h = hblk * 32 + (lane & 31);
  int kbase = kb * 16 + ((lane >> 5) << 3);
  float val[8];
  if (mid < 4) {
    const float* wq = Wq + (size_t)mid * 16384;
    const float* wk = Wk + (size_t)mid * 16384 + (size_t)hblk * 32 * 128;
    for (int idx = t; idx < 16384; idx += 512)
      WqS[(idx >> 7) * 129 + (idx & 127)] = wq[idx];
    for (int idx = t; idx < 4096; idx += 512)
      WkS[(idx >> 7) * 129 + (idx & 127)] = wk[idx];
    __syncthreads();
    int hl = lane & 31;
    #pragma unroll
    for (int j = 0; j < 8; ++j) val[j] = 0.f;
    for (int c = 0; c < 128; ++c) {
      float wkv = WkS[hl * 129 + c];
      #pragma unroll
      for (int j = 0; j < 8; ++j)
        val[j] += WqS[(kbase + j) * 129 + c] * wkv;
    }
    if (t < 32) {
      float s = 0.f;
      const float* bql = bq + mid * 128;
      for (int c = 0; c < 128; ++c) s += WkS[t * 129 + c] * bql[c];
      u[mid * 128 + hblk * 32 + t] = 0.08838834764831845f * s;
    }
  } else {
    const float* src;
    int krows = 128;
    if (mid < 8)        src = Wvm + (size_t)(mid - 4) * 16384;
    else if (mid < 12)  src = Wvp + (size_t)(mid - 8) * 16384;
    else if (mid == 12) src = rp_W;
    else if (mid == 13) src = rp_W + 16384;
    else if (mid == 14) { src = emb_Wm; krows = 19; }
    else                { src = emb_Wp; krows = 19; }
    #pragma unroll
    for (int j = 0; j < 8; ++j) {
      int k = kbase + j;
      val[j] = (k < krows) ? src[(size_t)k * 128 + h] : 0.f;
    }
  }
  s16x8 H, L;
  #pragma unroll
  for (int j = 0; j < 8; ++j) {
    unsigned short hi = bfhi(val[j]);
    H[j] = (short)hi;
    L[j] = (short)bfhi(val[j] - bf2f(hi));
  }
  short* dst = ws + (size_t)mid * 65536 + ((hblk * 8 + kb) * 64 + lane) * 8;
  *(s16x8*)dst = H;
  *(s16x8*)(dst + 32768) = L;
}

// ---------------- main kernel ----------------
__global__ __launch_bounds__(512, 2)
void cpt_kernel(const float* __restrict__ atom_types,
                const float* __restrict__ coords,
                const int*   __restrict__ edge_index,
                const float* __restrict__ edge_attr,
                const float* __restrict__ emb_bm, const float* __restrict__ emb_bp,
                const float* __restrict__ bvm, const float* __restrict__ bvp,
                const float* __restrict__ We,  const float* __restrict__ be,
                const float* __restrict__ dist_scale,
                const float* __restrict__ ln_g, const float* __restrict__ ln_b,
                const float* __restrict__ rp_b,
                const float* __restrict__ h1_W, const float* __restrict__ h1_b,
                const float* __restrict__ h2_W, const float* __restrict__ h2_b,
                const short* __restrict__ wpre, const float* __restrict__ uArr,
                float* __restrict__ out)
{
  __shared__ __align__(16) short R1s[34816];
  __shared__ __align__(16) short R2s[34816];
  __shared__ __align__(16) float SCa[512];
  __shared__ __align__(16) float SCb[512];

  const int t = threadIdx.x, b = blockIdx.x;
  const int w = t >> 6, lane = t & 63, l31 = lane & 31, h5 = lane >> 5;
  const int wm = w >> 1, ttb = (w & 1) << 1;
  const int mblk = wm << 5;
  const float scale = 0.08838834764831845f;  // 1/sqrt(128)

  // ---- stage x (atom_types||coords, k padded to 32) into R1 as bf16 hi/lo ----
  if (t < 128) {
    const float* xr = atom_types + ((size_t)b * 128 + t) * 16;
    const float* cr = coords + ((size_t)b * 128 + t) * 3;
    float xv[19];
    float4 a0 = *(const float4*)xr,       a1 = *(const float4*)(xr + 4);
    float4 a2 = *(const float4*)(xr + 8), a3 = *(const float4*)(xr + 12);
    xv[0]=a0.x; xv[1]=a0.y; xv[2]=a0.z; xv[3]=a0.w;
    xv[4]=a1.x; xv[5]=a1.y; xv[6]=a1.z; xv[7]=a1.w;
    xv[8]=a2.x; xv[9]=a2.y; xv[10]=a2.z; xv[11]=a2.w;
    xv[12]=a3.x; xv[13]=a3.y; xv[14]=a3.z; xv[15]=a3.w;
    xv[16]=cr[0]; xv[17]=cr[1]; xv[18]=cr[2];
    #pragma unroll
    for (int k = 0; k < 32; ++k) {
      float v = (k < 19) ? xv[k] : 0.f;
      unsigned short hh = bfhi(v);
      R1s[t * STR + k] = (short)hh;
      R1s[LOFS + t * STR + k] = (short)bfhi(v - bf2f(hh));
    }
  }
  // hoist embedding kb0 W frags above the barrier (ride across bar_lds)
  s16x8 eMah, eMal, ePah, ePal;
  ldW(wpre + (size_t)14 * 65536, wm, 0, lane, eMah, eMal);
  ldW(wpre + (size_t)15 * 65536, wm, 0, lane, ePah, ePal);
  bar_lds();

  // ---- embedding via MFMA: magT/phT (TRANSPOSED: h=32wm+ROWP(reg), a=32(ttb+j)+l31) ----
  f32x16 magT[2], phT[2];
  {
    #pragma unroll
    for (int reg = 0; reg < 16; ++reg) {
      float bm = emb_bm[32 * wm + ROWP(reg)];
      float bp = emb_bp[32 * wm + ROWP(reg)];
      #pragma unroll
      for (int j = 0; j < 2; ++j) { magT[j][reg] = bm; phT[j][reg] = bp; }
    }
    gemmTW2p(magT, wpre + (size_t)14 * 65536, R1s, wm, 2, ttb, l31, h5, lane, eMah, eMal);
    gemmTW2p(phT,  wpre + (size_t)15 * 65536, R1s, wm, 2, ttb, l31, h5, lane, ePah, ePal);
  }

  // ---- layers ----
  for (int l = 0; l < 4; ++l) {
    const short* wpP  = wpre + (size_t)l * 65536;        // W' pack
    const short* wvmP = wpre + (size_t)(4 + l) * 65536;
    const short* wvpP = wpre + (size_t)(8 + l) * 65536;
    float* Bf = (float*)R2s;                             // 128x128 bias, [j][i]

    bar_lds();                                       // prior layer readers done
    #pragma unroll
    for (int j = 0; j < 2; ++j)
      stageB64(R1s, magT[j], 32 * (ttb + j) + l31, mblk, h5);  // mag[a][h] -> R1
    {
      float4 z4 = make_float4(0.f, 0.f, 0.f, 0.f);
      #pragma unroll
      for (int k = 0; k < 8; ++k) *(float4*)(Bf + (t + 512 * k) * 4) = z4;
    }
    // v partials: v_a = sum_h mag[a][h] * u[h]  (interleaved SCa[a*4+wm])
    {
      float ur[16];
      #pragma unroll
      for (int reg = 0; reg < 16; ++reg) ur[reg] = uArr[l * 128 + 32 * wm + ROWP(reg)];
      #pragma unroll
      for (int j = 0; j < 2; ++j) {
        float p = 0.f;
        #pragma unroll
        for (int reg = 0; reg < 16; ++reg) p += magT[j][reg] * ur[reg];
        p += __shfl_xor(p, 32);
        if (h5 == 0) SCa[(32 * (ttb + j) + l31) * 4 + wm] = p;
      }
    }
    // edge-bias global loads + T-GEMM kb0 W frags hoisted above the barrier
    int e0h[2], e1h[2]; float bvh[2];
    {
      float w0 = We[l*4], w1 = We[l*4+1], w2 = We[l*4+2], w3 = We[l*4+3];
      float bel = be[l], dsl = dist_scale[l];
      #pragma unroll
      for (int k = 0; k < 2; ++k) {
        int e = t + 512 * k;
        e0h[k] = edge_index[(size_t)b * 2048 + e];
        e1h[k] = edge_index[(size_t)b * 2048 + 1024 + e];
        float4 ea = *(const float4*)(edge_attr + ((size_t)b * 1024 + e) * 4);
        bvh[k] = ea.x*w0 + ea.y*w1 + ea.z*w2 + ea.w*w3 + bel + dsl*ea.x;
      }
    }
    s16x8 tAh, tAl;
    ldW(wpP, wm, 0, lane, tAh, tAl);
    bar_lds();                                       // mag/Bf-zero/v ready

    // edge bias scatter: Bf[j][i] += bval
    #pragma unroll
    for (int k = 0; k < 2; ++k)
      atomicAdd(&Bf[e1h[k] * 128 + e0h[k]], bvh[k]);

    // T = mag @ W'  (accT: m=b'=32wm+ROWP, n=i=32(ttb+j)+l31); mag stays in R1
    f32x16 accT[2];
    #pragma unroll
    for (int j = 0; j < 2; ++j)
      #pragma unroll
      for (int reg = 0; reg < 16; ++reg) accT[j][reg] = 0.f;
    gemmTW2p(accT, wpP, R1s, wm, 8, ttb, l31, h5, lane, tAh, tAl);
    bar_lds();                                       // atomics visible

    // accS init = bias[i][j] + v_j  (vj via ONE float4 broadcast read per reg)
    f32x16 accS[2];
    {
      float vj[16];
      #pragma unroll
      for (int reg = 0; reg < 16; ++reg) {
        int jj = 32 * wm + ROWP(reg);
        float4 v4 = *(const float4*)&SCa[jj * 4];
        vj[reg] = v4.x + v4.y + v4.z + v4.w;
      }
      #pragma unroll
      for (int j = 0; j < 2; ++j) {
        #pragma unroll
        for (int reg = 0; reg < 16; ++reg)
          accS[j][reg] = Bf[(32 * wm + ROWP(reg)) * 128 + 32 * (ttb + j) + l31] + vj[reg];
      }
    }
    bar_lds();                                       // Bf reads done
    #pragma unroll
    for (int j = 0; j < 2; ++j)
      stageB64s(R2s, accT[j], 32 * (ttb + j) + l31, mblk, h5, scale);  // Ts -> R2
    bar_lds();                                       // Ts ready

    // scoresT[j][i] = mag @ Ts^T + bias + v
    gemmLL2(accS, R1s, R2s, mblk, ttb, l31, h5);

    // one-pass softmax over j: local (max, expsum) -> ONE barrier -> merge
    float mloc[2];
    #pragma unroll
    for (int j = 0; j < 2; ++j) {
      float m = accS[j][0];
      #pragma unroll
      for (int reg = 1; reg < 16; ++reg) m = fmaxf(m, accS[j][reg]);
      m = fmaxf(m, __shfl_xor(m, 32));
      mloc[j] = m;
      float s = 0.f;
      #pragma unroll
      for (int reg = 0; reg < 16; ++reg) {
        float e = __expf(accS[j][reg] - m);
        accS[j][reg] = e; s += e;
      }
      s += __shfl_xor(s, 32);
      if (h5 == 0) {
        SCa[(32 * (ttb + j) + l31) * 4 + wm] = m;
        SCb[(32 * (ttb + j) + l31) * 4 + wm] = s;
      }
    }
    bar_lds();                                       // (also: all Ts reads done)
    #pragma unroll
    for (int j = 0; j < 2; ++j) {
      int i = 32 * (ttb + j) + l31;
      float4 m4 = *(const float4*)&SCa[i * 4];
      float4 s4 = *(const float4*)&SCb[i * 4];
      float M = fmaxf(fmaxf(m4.x, m4.y), fmaxf(m4.z, m4.w));
      float S = s4.x * __expf(m4.x - M) + s4.y * __expf(m4.y - M)
              + s4.z * __expf(m4.z - M) + s4.w * __expf(m4.w - M);
      float f = __expf(mloc[j] - M) / S;
      #pragma unroll
      for (int reg = 0; reg < 16; ++reg) accS[j][reg] *= f;
    }
    #pragma unroll
    for (int j = 0; j < 2; ++j)
      stageB64(R2s, accS[j], 32 * (ttb + j) + l31, mblk, h5);  // attn[i][j] -> R2

    // vm = mag @ Wvm (mag still resident in R1 — no restage)
    {
      f32x16 accVM[2];
      #pragma unroll
      for (int j = 0; j < 2; ++j) {
        float bv = bvm[l * 128 + 32 * (ttb + j) + l31];
        #pragma unroll
        for (int reg = 0; reg < 16; ++reg) accVM[j][reg] = bv;
      }
      gemmNW2(accVM, R1s, wvmP, mblk, ttb, l31, h5, lane);
      bar_lds();                                     // all mag reads done
      #pragma unroll
      for (int j = 0; j < 2; ++j)
        stageB64(R1s, accVM[j], 32 * (ttb + j) + l31, mblk, h5); // vmT[h][j] -> R1
      bar_lds();                                     // vm + attn ready
    }

    // new_mag^T = vm^T @ attn^T + mag^T  (accM: h=32wm+ROWP, i=32(ttb+j)+l31)
    f32x16 accM[2];
    #pragma unroll
    for (int j = 0; j < 2; ++j) accM[j] = magT[j];
    gemmLL2(accM, R1s, R2s, mblk, ttb, l31, h5);

    // LayerNorm over h: interleaved partials, ONE float4 read per (j)
    {
      #pragma unroll
      for (int j = 0; j < 2; ++j) {
        float s = 0.f, q = 0.f;
        #pragma unroll
        for (int reg = 0; reg < 16; ++reg) { float v = accM[j][reg]; s += v; q += v*v; }
        s += __shfl_xor(s, 32); q += __shfl_xor(q, 32);
        if (h5 == 0) {
          SCa[(32 * (ttb + j) + l31) * 4 + wm] = s;
          SCb[(32 * (ttb + j) + l31) * 4 + wm] = q;
        }
      }
      bar_lds();
      float mu_[2], inv_[2];
      #pragma unroll
      for (int j = 0; j < 2; ++j) {
        int i = 32 * (ttb + j) + l31;
        float4 s4 = *(const float4*)&SCa[i * 4];
        float4 q4 = *(const float4*)&SCb[i * 4];
        float s = s4.x + s4.y + s4.z + s4.w;
        float q = q4.x + q4.y + q4.z + q4.w;
        float mu = s * (1.f / 128.f);
        float var = q * (1.f / 128.f) - mu * mu;
        mu_[j] = mu;
        inv_[j] = 1.f / sqrtf(var + 1e-5f);
      }
      #pragma unroll
      for (int reg = 0; reg < 16; ++reg) {
        float gv = ln_g[l * 128 + 32 * wm + ROWP(reg)];
        float bv = ln_b[l * 128 + 32 * wm + ROWP(reg)];
        #pragma unroll
        for (int j = 0; j < 2; ++j)
          magT[j][reg] = gv * ((accM[j][reg] - mu_[j]) * inv_[j]) + bv;
      }
    }
    #pragma unroll
    for (int j = 0; j < 2; ++j)
      stageB64(R1s, phT[j], 32 * (ttb + j) + l31, mblk, h5);   // ph[a][h] -> R1
    bar_lds();

    // vp = ph @ Wvp (normal); staged as vpT[h][j]
    {
      f32x16 accV[2];
      #pragma unroll
      for (int j = 0; j < 2; ++j) {
        float bv = bvp[l * 128 + 32 * (ttb + j) + l31];
        #pragma unroll
        for (int reg = 0; reg < 16; ++reg) accV[j][reg] = bv;
      }
      gemmNW2(accV, R1s, wvpP, mblk, ttb, l31, h5, lane);
      bar_lds();                                     // all ph reads done
      #pragma unroll
      for (int j = 0; j < 2; ++j)
        stageB64(R1s, accV[j], 32 * (ttb + j) + l31, mblk, h5); // vpT[h][j] -> R1
      bar_lds();
    }

    // new_ph^T = vp^T @ attn^T + ph^T
    f32x16 accP[2];
    #pragma unroll
    for (int j = 0; j < 2; ++j) accP[j] = phT[j];
    gemmLL2(accP, R1s, R2s, mblk, ttb, l31, h5);
    #pragma unroll
    for (int j = 0; j < 2; ++j) phT[j] = accP[j];
  } // layers

  // ---- real/imag -> RealProjection (transposed accR: hout=32wm+ROWP, a=32(ttb+j)+l31) ----
  f32x16 reT[2], imT[2];
  #pragma unroll
  for (int j = 0; j < 2; ++j)
    #pragma unroll
    for (int reg = 0; reg < 16; ++reg) {
      float s_, c_;
      __sincosf(phT[j][reg], &s_, &c_);
      reT[j][reg] = magT[j][reg] * c_;
      imT[j][reg] = magT[j][reg] * s_;
    }
  bar_lds();
  #pragma unroll
  for (int j = 0; j < 2; ++j) {
    stageB64(R1s, reT[j], 32 * (ttb + j) + l31, mblk, h5);   // re[a][h] -> R1
    stageB64(R2s, imT[j], 32 * (ttb + j) + l31, mblk, h5);   // im[a][h] -> R2
  }
  // hoist rp kb0 W frags above the barrier
  s16x8 rAah, rAal, rBah, rBal;
  ldW(wpre + (size_t)12 * 65536, wm, 0, lane, rAah, rAal);
  ldW(wpre + (size_t)13 * 65536, wm, 0, lane, rBah, rBal);
  bar_lds();
  f32x16 accR[2];
  #pragma unroll
  for (int reg = 0; reg < 16; ++reg) {
    float bv = rp_b[32 * wm + ROWP(reg)];
    #pragma unroll
    for (int j = 0; j < 2; ++j) accR[j][reg] = bv;
  }
  gemmTW2p(accR, wpre + (size_t)12 * 65536, R1s, wm, 8, ttb, l31, h5, lane, rAah, rAal);
  gemmTW2p(accR, wpre + (size_t)13 * 65536, R2s, wm, 8, ttb, l31, h5, lane, rBah, rBal);

  // ---- pooling: column sum over atoms a (old 2x128 layout — runs once) ----
  {
    float cs[16];
    #pragma unroll
    for (int reg = 0; reg < 16; ++reg) {
      float s = accR[0][reg] + accR[1][reg];
      s += __shfl_xor(s, 16); s += __shfl_xor(s, 8);
      s += __shfl_xor(s, 4);  s += __shfl_xor(s, 2); s += __shfl_xor(s, 1);
      cs[reg] = s;
    }
    if (l31 == 0) {
      #pragma unroll
      for (int reg = 0; reg < 16; ++reg)
        SCa[(w & 1) * 128 + 32 * wm + ROWP(reg)] = cs[reg];
    }
  }
  bar_lds();
  // h1 GEMV split 4-way over all 512 threads; combine via SCb
  {
    int col = t & 127, seg = t >> 7;
    float acc = (seg == 0) ? h1_b[col] : 0.f;
    int i0 = seg * 32;
    for (int i = i0; i < i0 + 32; ++i) {
      float c = SCa[i] + SCa[128 + i];
      acc += c * (h1_W[(size_t)i * 128 + col] * (1.f / 128.f) +
                  h1_W[(size_t)(128 + i) * 128 + col]);
    }
    SCb[t] = acc;
  }
  bar_lds();
  if (t < 128) {
    float a = SCb[t] + SCb[128 + t] + SCb[256 + t] + SCb[384 + t];
    float hv = a / (1.f + __expf(-a));   // SiLU
    SCa[t] = hv * h2_W[t];
  }
  bar_lds();
  if (t < 64) {
    float s2 = SCa[t] + SCa[64 + t];
    #pragma unroll
    for (int off = 32; off >= 1; off >>= 1) s2 += __shfl_xor(s2, off);
    if (t == 0) out[b] = s2 + h2_b[0];
  }
}

extern "C" void kernel_launch(void* const* d_in, const int* in_sizes, int n_in,
                              void* d_out, int out_size, void* d_ws, size_t ws_size,
                              hipStream_t stream) {
  const float* atom_types = (const float*)d_in[0];
  const float* coords     = (const float*)d_in[1];
  const int*   edge_index = (const int*)  d_in[2];
  const float* edge_attr  = (const float*)d_in[3];
  const float* emb_Wm = (const float*)d_in[4];
  const float* emb_bm = (const float*)d_in[5];
  const float* emb_Wp = (const float*)d_in[6];
  const float* emb_bp = (const float*)d_in[7];
  const float* Wq  = (const float*)d_in[8];
  const float* bq  = (const float*)d_in[9];
  const float* Wk  = (const float*)d_in[10];
  const float* bk  = (const float*)d_in[11];
  const float* Wvm = (const float*)d_in[12];
  const float* bvm = (const float*)d_in[13];
  const float* Wvp = (const float*)d_in[14];
  const float* bvp = (const float*)d_in[15];
  const float* We  = (const float*)d_in[16];
  const float* be  = (const float*)d_in[17];
  const float* dist_scale = (const float*)d_in[18];
  const float* ln_g = (const float*)d_in[19];
  const float* ln_b = (const float*)d_in[20];
  const float* rp_W = (const float*)d_in[21];
  const float* rp_b = (const float*)d_in[22];
  const float* h1_W = (const float*)d_in[23];
  const float* h1_b = (const float*)d_in[24];
  const float* h2_W = (const float*)d_in[25];
  const float* h2_b = (const float*)d_in[26];
  float* out = (float*)d_out;
  (void)bk;
  // workspace layout: 16 packed mats (16*131072 B) | u (512 f32)
  short* wpre = (short*)d_ws;
  float* uArr = (float*)((char*)d_ws + (size_t)16 * 131072);

  hipLaunchKernelGGL(prep_kernel, dim3(64), dim3(512), 0, stream,
                     Wq, Wk, bq, Wvm, Wvp, rp_W, emb_Wm, emb_Wp, wpre, uArr);
  hipLaunchKernelGGL(cpt_kernel, dim3(1024), dim3(512), 0, stream,
                     atom_types, coords, edge_index, edge_attr,
                     emb_bm, emb_bp,
                     bvm, bvp,
                     We, be, dist_scale, ln_g, ln_b,
                     rp_b, h1_W, h1_b, h2_W, h2_b,
                     (const short*)wpre, (const float*)uArr, out);
}